// Round 4
// baseline (396.667 us; speedup 1.0000x reference)
//
#include <hip/hip_runtime.h>
#include <hip/hip_bf16.h>

typedef __attribute__((ext_vector_type(8))) short short8;
typedef __attribute__((ext_vector_type(4))) float f32x4;

#define N_BATCH 8
#define N_ROWS 32768
#define DDIM 128
#define KSLOT 64
#define EH 128
#define SCALE 0.08838834764831845f

__device__ inline unsigned short f2bf(float f){
  unsigned int u = __builtin_bit_cast(unsigned int, f);
  u = (u + 0x7FFFu + ((u >> 16) & 1u)) >> 16;
  return (unsigned short)u;
}
__device__ inline float bf2f(unsigned short h){
  unsigned int u = ((unsigned int)h) << 16;
  return __builtin_bit_cast(float, u);
}

// ---- prep: Wk/Wv -> bf16 transposed [e][d] ----
__global__ void prep_w_kernel(const float* __restrict__ Wk, const float* __restrict__ Wv,
                              unsigned short* __restrict__ WkT, unsigned short* __restrict__ WvT){
  int e = blockIdx.x & 127;
  const float* W = (blockIdx.x & 128) ? Wv : Wk;
  unsigned short* T = (blockIdx.x & 128) ? WvT : WkT;
  int d = threadIdx.x;
  T[e * 128 + d] = f2bf(W[d * 128 + e]);
}

// ---- prep: q = S @ Wq (fp32 math) -> bf16 [b][slot][e] ----
__global__ void prep_q_kernel(const float* __restrict__ S, const float* __restrict__ Wq,
                              unsigned short* __restrict__ qbf){
  int bs = blockIdx.x; // 0..511 = b*64+slot
  __shared__ float srow[128];
  int e = threadIdx.x;
  srow[e] = S[bs * 128 + e];
  __syncthreads();
  float acc = 0.f;
  #pragma unroll 8
  for(int h = 0; h < 128; ++h) acc += srow[h] * Wq[h * 128 + e];
  qbf[bs * 128 + e] = f2bf(acc);
}

// ---- main fused kernel: one (or tpb) 64-row tile(s) per block ----
__global__ __launch_bounds__(256, 2) void sse_main_kernel(
    const float* __restrict__ X, const unsigned short* __restrict__ WkT,
    const unsigned short* __restrict__ WvT, const unsigned short* __restrict__ qbf,
    unsigned short* __restrict__ partials, int tpb, int perb)
{
  __shared__ unsigned short Ks[64][136];   // k tile [n][e]; reused to stage S_hat partial
  __shared__ unsigned short Vts[128][72];  // v tile transposed [e][n]
  __shared__ unsigned short WTs[64][72];   // W transposed [slot][n]

  const int tid  = threadIdx.x;
  const int wave = tid >> 6;
  const int lane = tid & 63;
  const int l15  = lane & 15;
  const int g    = lane >> 4;

  const int blk = blockIdx.x;
  const int b   = blk / perb;
  const int t0  = (blk % perb) * tpb;

  const float* Xb = X + (size_t)b * N_ROWS * DDIM;
  const unsigned short* qb = qbf + b * KSLOT * EH;

  f32x4 sacc[8];
  #pragma unroll
  for(int i = 0; i < 8; ++i) sacc[i] = {0.f, 0.f, 0.f, 0.f};

  for(int tt = 0; tt < tpb; ++tt){
    const int row0 = (t0 + tt) * 64 + wave * 16;

    // ---- phase 1: load+pack X A-frags (4 steps) ----
    short8 a4[4];
    #pragma unroll
    for(int step = 0; step < 4; ++step){
      const float* px = Xb + (size_t)(row0 + l15) * DDIM + step * 32 + g * 8;
      f32x4 x0 = *reinterpret_cast<const f32x4*>(px);
      f32x4 x1 = *reinterpret_cast<const f32x4*>(px + 4);
      short8 a;
      a[0]=(short)f2bf(x0[0]); a[1]=(short)f2bf(x0[1]); a[2]=(short)f2bf(x0[2]); a[3]=(short)f2bf(x0[3]);
      a[4]=(short)f2bf(x1[0]); a[5]=(short)f2bf(x1[1]); a[6]=(short)f2bf(x1[2]); a[7]=(short)f2bf(x1[3]);
      a4[step] = a;
    }

    // k/v strips in et-chunks of 4, k and v in separate passes
    #pragma unroll
    for(int etc = 0; etc < 2; ++etc){
      {
        f32x4 acc[4];
        #pragma unroll
        for(int i = 0; i < 4; ++i) acc[i] = {0.f,0.f,0.f,0.f};
        #pragma unroll
        for(int step = 0; step < 4; ++step){
          #pragma unroll
          for(int e4 = 0; e4 < 4; ++e4){
            const int et = etc * 4 + e4;
            short8 bk = *reinterpret_cast<const short8*>(WkT + (et * 16 + l15) * DDIM + step * 32 + g * 8);
            acc[e4] = __builtin_amdgcn_mfma_f32_16x16x32_bf16(a4[step], bk, acc[e4], 0, 0, 0);
          }
        }
        #pragma unroll
        for(int e4 = 0; e4 < 4; ++e4){
          const int et = etc * 4 + e4;
          #pragma unroll
          for(int r = 0; r < 4; ++r)
            Ks[wave * 16 + g * 4 + r][et * 16 + l15] = f2bf(acc[e4][r]);
        }
      }
      {
        f32x4 acc[4];
        #pragma unroll
        for(int i = 0; i < 4; ++i) acc[i] = {0.f,0.f,0.f,0.f};
        #pragma unroll
        for(int step = 0; step < 4; ++step){
          #pragma unroll
          for(int e4 = 0; e4 < 4; ++e4){
            const int et = etc * 4 + e4;
            short8 bv = *reinterpret_cast<const short8*>(WvT + (et * 16 + l15) * DDIM + step * 32 + g * 8);
            acc[e4] = __builtin_amdgcn_mfma_f32_16x16x32_bf16(a4[step], bv, acc[e4], 0, 0, 0);
          }
        }
        #pragma unroll
        for(int e4 = 0; e4 < 4; ++e4){
          const int et = etc * 4 + e4;
          ushort4 vp;
          vp.x = f2bf(acc[e4][0]); vp.y = f2bf(acc[e4][1]);
          vp.z = f2bf(acc[e4][2]); vp.w = f2bf(acc[e4][3]);
          *reinterpret_cast<ushort4*>(&Vts[et * 16 + l15][wave * 16 + g * 4]) = vp;
        }
      }
    }

    // ---- phase 2: M = k q^T, sigmoid-normalize -> WTs ----
    f32x4 macc[4];
    #pragma unroll
    for(int i = 0; i < 4; ++i) macc[i] = {0.f,0.f,0.f,0.f};
    #pragma unroll
    for(int step = 0; step < 4; ++step){
      short8 a = *reinterpret_cast<const short8*>(&Ks[wave * 16 + l15][step * 32 + g * 8]);
      #pragma unroll
      for(int st = 0; st < 4; ++st){
        short8 bq = *reinterpret_cast<const short8*>(qb + (st * 16 + l15) * EH + step * 32 + g * 8);
        macc[st] = __builtin_amdgcn_mfma_f32_16x16x32_bf16(a, bq, macc[st], 0, 0, 0);
      }
    }
    float att[4][4];
    float rowsum[4];
    #pragma unroll
    for(int st = 0; st < 4; ++st){
      #pragma unroll
      for(int r = 0; r < 4; ++r)
        att[st][r] = 1.f / (1.f + __expf(-SCALE * macc[st][r])) + 1e-8f;
    }
    #pragma unroll
    for(int r = 0; r < 4; ++r){
      float s = att[0][r] + att[1][r] + att[2][r] + att[3][r];
      s += __shfl_xor(s, 1); s += __shfl_xor(s, 2);
      s += __shfl_xor(s, 4); s += __shfl_xor(s, 8);
      rowsum[r] = s;
    }
    #pragma unroll
    for(int st = 0; st < 4; ++st){
      ushort4 wp;
      wp.x = f2bf(att[st][0] / rowsum[0]);
      wp.y = f2bf(att[st][1] / rowsum[1]);
      wp.z = f2bf(att[st][2] / rowsum[2]);
      wp.w = f2bf(att[st][3] / rowsum[3]);
      *reinterpret_cast<ushort4*>(&WTs[st * 16 + l15][wave * 16 + g * 4]) = wp;
    }
    __syncthreads();  // all waves' Vts + WTs complete

    // ---- phase 3: S_hat += W^T v ----
    #pragma unroll
    for(int ns = 0; ns < 2; ++ns){
      short8 a = *reinterpret_cast<const short8*>(&WTs[wave * 16 + l15][ns * 32 + g * 8]);
      #pragma unroll
      for(int et = 0; et < 8; ++et){
        short8 bvt = *reinterpret_cast<const short8*>(&Vts[et * 16 + l15][ns * 32 + g * 8]);
        sacc[et] = __builtin_amdgcn_mfma_f32_16x16x32_bf16(a, bvt, sacc[et], 0, 0, 0);
      }
    }
    __syncthreads();  // protect Vts/WTs before next iteration
  }

  // ---- stage S_hat partial (bf16) into Ks, then coalesced copy-out ----
  #pragma unroll
  for(int et = 0; et < 8; ++et){
    #pragma unroll
    for(int r = 0; r < 4; ++r)
      Ks[wave * 16 + g * 4 + r][et * 16 + l15] = f2bf(sacc[et][r]);
  }
  __syncthreads();
  unsigned short* po = partials + (size_t)blk * 8192;
  #pragma unroll
  for(int c = 0; c < 4; ++c){
    int chunk = tid + 256 * c;        // ushort8 chunk 0..1023
    int row = chunk >> 4;
    int col = (chunk & 15) * 8;
    *reinterpret_cast<short8*>(po + chunk * 8) =
        *reinterpret_cast<const short8*>(&Ks[row][col]);
  }
}

// ---- reduce stage 1: sum groups of tiles (bf16 in, f32 out) ----
__global__ void reduce1_kernel(const unsigned short* __restrict__ partials,
                               float* __restrict__ partial2, int perb, int gs){
  // grid: 8 b x 16 tg x 4 chunk
  int bi = blockIdx.x;
  int chunk = bi & 3;
  int tg = (bi >> 2) & 15;
  int b  = bi >> 6;
  int tid = threadIdx.x;
  int off = chunk * 2048 + tid * 8;
  float acc[8];
  #pragma unroll
  for(int j = 0; j < 8; ++j) acc[j] = 0.f;
  for(int i = 0; i < gs; ++i){
    int blkidx = b * perb + tg * gs + i;
    short8 p = *reinterpret_cast<const short8*>(partials + (size_t)blkidx * 8192 + off);
    #pragma unroll
    for(int j = 0; j < 8; ++j) acc[j] += bf2f((unsigned short)p[j]);
  }
  float* po = partial2 + ((size_t)(b * 16 + tg)) * 8192 + off;
  #pragma unroll
  for(int j = 0; j < 8; ++j) po[j] = acc[j];
}

// ---- reduce stage 2: final sum over 16 groups ----
__global__ void reduce2_kernel(const float* __restrict__ partial2, float* __restrict__ out){
  int idx = blockIdx.x * 256 + threadIdx.x; // 0..65535
  int b   = idx >> 13;
  int rem = idx & 8191;
  float s = 0.f;
  #pragma unroll
  for(int gct = 0; gct < 16; ++gct)
    s += partial2[((size_t)(b * 16 + gct)) * 8192 + rem];
  out[idx] = s;
}

extern "C" void kernel_launch(void* const* d_in, const int* in_sizes, int n_in,
                              void* d_out, int out_size, void* d_ws, size_t ws_size,
                              hipStream_t stream){
  const float* X  = (const float*)d_in[0];
  const float* S  = (const float*)d_in[1];
  const float* Wk = (const float*)d_in[2];
  const float* Wq = (const float*)d_in[3];
  const float* Wv = (const float*)d_in[4];
  float* out = (float*)d_out;

  char* ws = (char*)d_ws;
  unsigned short* WkT = (unsigned short*)(ws);
  unsigned short* WvT = (unsigned short*)(ws + 32768);
  unsigned short* qbf = (unsigned short*)(ws + 65536);
  float* partial2     = (float*)(ws + 196608);                 // 4 MB
  unsigned short* partials = (unsigned short*)(ws + 196608 + 4194304);

  // pick tiles-per-block so partials fit the workspace
  int tpb = 1;
  while(tpb < 512 &&
        (size_t)196608 + 4194304 + (size_t)(4096 / tpb) * 16384 > ws_size) tpb <<= 1;
  int perb = 512 / tpb;          // blocks per batch
  int nblk = N_BATCH * perb;
  int gs   = perb / 16;          // blocks summed per reduce1 group

  hipLaunchKernelGGL(prep_w_kernel, dim3(256), dim3(128), 0, stream, Wk, Wv, WkT, WvT);
  hipLaunchKernelGGL(prep_q_kernel, dim3(512), dim3(128), 0, stream, S, Wq, qbf);
  hipLaunchKernelGGL(sse_main_kernel, dim3(nblk), dim3(256), 0, stream,
                     X, WkT, WvT, qbf, partials, tpb, perb);
  hipLaunchKernelGGL(reduce1_kernel, dim3(512), dim3(256), 0, stream, partials, partial2, perb, gs);
  hipLaunchKernelGGL(reduce2_kernel, dim3(256), dim3(256), 0, stream, partial2, out);
}

// Round 5
// 93.918 us; speedup vs baseline: 4.2235x; 4.2235x over previous
//
#include <hip/hip_runtime.h>
#include <hip/hip_bf16.h>

typedef __attribute__((ext_vector_type(8))) short short8;
typedef __attribute__((ext_vector_type(4))) float f32x4;

#define N_BATCH 8
#define N_ROWS 32768
#define DDIM 128
#define KSLOT 64
#define EH 128
#define SCALE 0.08838834764831845f

__device__ inline unsigned short f2bf(float f){
  unsigned int u = __builtin_bit_cast(unsigned int, f);
  u = (u + 0x7FFFu + ((u >> 16) & 1u)) >> 16;
  return (unsigned short)u;
}

// ---- prep: qk[b][s][d] = scale * (S[b,s,:]@Wq) @ Wk^T, bf16 ----
__global__ void prep_qk_kernel(const float* __restrict__ S, const float* __restrict__ Wq,
                               const float* __restrict__ Wk, unsigned short* __restrict__ qk){
  int bs = blockIdx.x;             // 0..511 = b*64 + slot
  __shared__ float srow[128];
  __shared__ float qrow[128];
  int t = threadIdx.x;             // 128 threads
  srow[t] = S[bs * 128 + t];
  __syncthreads();
  float acc = 0.f;
  #pragma unroll 8
  for(int h = 0; h < 128; ++h) acc += srow[h] * Wq[h * 128 + t];   // q[s,e=t]
  qrow[t] = acc;
  __syncthreads();
  float acc2 = 0.f;
  #pragma unroll 8
  for(int e = 0; e < 128; ++e) acc2 += qrow[e] * Wk[t * 128 + e];  // qk[s,d=t]
  qk[bs * 128 + t] = f2bf(acc2 * SCALE);
}

// ---- main fused kernel: M = X@qk^T -> sigmoid-norm W -> T += W^T @ X ----
__global__ __launch_bounds__(256, 2) void sse_main_kernel(
    const float* __restrict__ X, const unsigned short* __restrict__ qk,
    float* __restrict__ partials, int B_n)
{
  __shared__ unsigned short Xt[128][72];   // X tile transposed [d][row], bf16
  __shared__ unsigned short WTs[64][72];   // W transposed [slot][row], bf16

  const int tid  = threadIdx.x;
  const int wave = tid >> 6;
  const int lane = tid & 63;
  const int l15  = lane & 15;
  const int g    = lane >> 4;

  const int b  = blockIdx.x / B_n;
  const int bb = blockIdx.x % B_n;

  const float* Xb = X + (size_t)b * N_ROWS * DDIM;
  const unsigned short* qkb = qk + b * KSLOT * EH;

  f32x4 sacc[8];   // T[slot-tile=wave][all d]: slot=wave*16+g*4+r, d=et*16+l15
  #pragma unroll
  for(int i = 0; i < 8; ++i) sacc[i] = {0.f, 0.f, 0.f, 0.f};

  for(int t = bb; t < N_ROWS / 64; t += B_n){
    const int row0 = t * 64 + wave * 16;

    // ---- load X strip (16 rows/wave), pack bf16 A-frags, store transposed to LDS ----
    short8 a4[4];
    #pragma unroll
    for(int step = 0; step < 4; ++step){
      const float* px = Xb + (size_t)(row0 + l15) * DDIM + step * 32 + g * 8;
      f32x4 x0 = *reinterpret_cast<const f32x4*>(px);
      f32x4 x1 = *reinterpret_cast<const f32x4*>(px + 4);
      short8 a;
      a[0]=(short)f2bf(x0[0]); a[1]=(short)f2bf(x0[1]); a[2]=(short)f2bf(x0[2]); a[3]=(short)f2bf(x0[3]);
      a[4]=(short)f2bf(x1[0]); a[5]=(short)f2bf(x1[1]); a[6]=(short)f2bf(x1[2]); a[7]=(short)f2bf(x1[3]);
      a4[step] = a;
      #pragma unroll
      for(int j = 0; j < 8; ++j)
        Xt[step * 32 + g * 8 + j][wave * 16 + l15] = (unsigned short)a[j];
    }

    // ---- phase A: M-tile = X @ qk^T (B-frags from global, L2-hot) ----
    f32x4 macc[4];
    #pragma unroll
    for(int i = 0; i < 4; ++i) macc[i] = {0.f,0.f,0.f,0.f};
    #pragma unroll
    for(int step = 0; step < 4; ++step){
      #pragma unroll
      for(int st = 0; st < 4; ++st){
        short8 bq = *reinterpret_cast<const short8*>(qkb + (st * 16 + l15) * EH + step * 32 + g * 8);
        macc[st] = __builtin_amdgcn_mfma_f32_16x16x32_bf16(a4[step], bq, macc[st], 0, 0, 0);
      }
    }

    // ---- sigmoid + eps, normalize over 64 slots, W^T -> LDS ----
    float att[4][4];
    float rowsum[4];
    #pragma unroll
    for(int st = 0; st < 4; ++st){
      #pragma unroll
      for(int r = 0; r < 4; ++r)
        att[st][r] = 1.f / (1.f + __expf(-macc[st][r])) + 1e-8f;   // scale folded into qk
    }
    #pragma unroll
    for(int r = 0; r < 4; ++r){
      float s = att[0][r] + att[1][r] + att[2][r] + att[3][r];
      s += __shfl_xor(s, 1); s += __shfl_xor(s, 2);
      s += __shfl_xor(s, 4); s += __shfl_xor(s, 8);
      rowsum[r] = s;
    }
    #pragma unroll
    for(int st = 0; st < 4; ++st){
      ushort4 wp;
      wp.x = f2bf(att[st][0] / rowsum[0]);
      wp.y = f2bf(att[st][1] / rowsum[1]);
      wp.z = f2bf(att[st][2] / rowsum[2]);
      wp.w = f2bf(att[st][3] / rowsum[3]);
      *reinterpret_cast<ushort4*>(&WTs[st * 16 + l15][wave * 16 + g * 4]) = wp;
    }
    __syncthreads();   // Xt + WTs complete across all waves

    // ---- phase B: T += W^T @ X   (A=WTs[slot][row], B=Xt[d][row], k=row) ----
    #pragma unroll
    for(int ns = 0; ns < 2; ++ns){
      short8 af = *reinterpret_cast<const short8*>(&WTs[wave * 16 + l15][ns * 32 + g * 8]);
      #pragma unroll
      for(int et = 0; et < 8; ++et){
        short8 bf = *reinterpret_cast<const short8*>(&Xt[et * 16 + l15][ns * 32 + g * 8]);
        sacc[et] = __builtin_amdgcn_mfma_f32_16x16x32_bf16(af, bf, sacc[et], 0, 0, 0);
      }
    }
    __syncthreads();   // protect Xt/WTs before next iteration overwrites
  }

  // ---- write per-block partial T [64 slot][128 d] f32 ----
  float* po = partials + (size_t)blockIdx.x * (KSLOT * EH);
  #pragma unroll
  for(int et = 0; et < 8; ++et){
    #pragma unroll
    for(int r = 0; r < 4; ++r)
      po[(wave * 16 + g * 4 + r) * EH + et * 16 + l15] = sacc[et][r];
  }
}

// ---- reduce partials over blocks, then S_hat = T @ Wv ----
__global__ void reduce_kernel(const float* __restrict__ partials, const float* __restrict__ Wv,
                              float* __restrict__ out, int B_n){
  int bs = blockIdx.x;             // 0..511 = b*64 + slot
  int b  = bs >> 6;
  int s  = bs & 63;
  __shared__ float Tl[128];
  int t = threadIdx.x;             // 128 threads = d, then e
  float acc = 0.f;
  for(int i = 0; i < B_n; ++i)
    acc += partials[((size_t)(b * B_n + i) * KSLOT + s) * EH + t];
  Tl[t] = acc;
  __syncthreads();
  float o = 0.f;
  #pragma unroll 8
  for(int d = 0; d < 128; ++d) o += Tl[d] * Wv[d * 128 + t];
  out[bs * 128 + t] = o;
}

extern "C" void kernel_launch(void* const* d_in, const int* in_sizes, int n_in,
                              void* d_out, int out_size, void* d_ws, size_t ws_size,
                              hipStream_t stream){
  const float* X  = (const float*)d_in[0];
  const float* S  = (const float*)d_in[1];
  const float* Wk = (const float*)d_in[2];
  const float* Wq = (const float*)d_in[3];
  const float* Wv = (const float*)d_in[4];
  float* out = (float*)d_out;

  char* ws = (char*)d_ws;
  unsigned short* qk = (unsigned short*)(ws);              // 128 KB
  float* partials    = (float*)(ws + 131072);

  int B_n = 128;   // blocks per batch
  while(B_n > 1 && (size_t)131072 + (size_t)N_BATCH * B_n * KSLOT * EH * 4 > ws_size) B_n >>= 1;

  hipLaunchKernelGGL(prep_qk_kernel, dim3(512), dim3(128), 0, stream, S, Wq, Wk, qk);
  hipLaunchKernelGGL(sse_main_kernel, dim3(N_BATCH * B_n), dim3(256), 0, stream,
                     X, qk, partials, B_n);
  hipLaunchKernelGGL(reduce_kernel, dim3(512), dim3(128), 0, stream, partials, Wv, out, B_n);
}

// Round 6
// 93.773 us; speedup vs baseline: 4.2301x; 1.0016x over previous
//
#include <hip/hip_runtime.h>
#include <hip/hip_bf16.h>

typedef __attribute__((ext_vector_type(8))) short short8;
typedef __attribute__((ext_vector_type(4))) float f32x4;

#define N_BATCH 8
#define N_ROWS 32768
#define DDIM 128
#define KSLOT 64
#define EH 128
#define TILES_PER_B 512        // N_ROWS/64
#define SCALE 0.08838834764831845f

__device__ inline unsigned short f2bf(float f){
  unsigned int u = __builtin_bit_cast(unsigned int, f);
  u = (u + 0x7FFFu + ((u >> 16) & 1u)) >> 16;
  return (unsigned short)u;
}
__device__ inline float bf2f(unsigned short h){
  unsigned int u = ((unsigned int)h) << 16;
  return __builtin_bit_cast(float, u);
}

// ---- prep: qk[b][s][d] = scale * (S[b,s,:]@Wq) @ Wk^T, bf16 ----
__global__ void prep_qk_kernel(const float* __restrict__ S, const float* __restrict__ Wq,
                               const float* __restrict__ Wk, unsigned short* __restrict__ qk){
  int bs = blockIdx.x;             // 0..511 = b*64 + slot
  __shared__ float srow[128];
  __shared__ float qrow[128];
  int t = threadIdx.x;             // 128 threads
  srow[t] = S[bs * 128 + t];
  __syncthreads();
  float acc = 0.f;
  #pragma unroll 8
  for(int h = 0; h < 128; ++h) acc += srow[h] * Wq[h * 128 + t];   // q[s,e=t]
  qrow[t] = acc;
  __syncthreads();
  float acc2 = 0.f;
  #pragma unroll 8
  for(int e = 0; e < 128; ++e) acc2 += qrow[e] * Wk[t * 128 + e];  // qk[s,d=t]
  qk[bs * 128 + t] = f2bf(acc2 * SCALE);
}

// ---- main fused kernel: ONE 64-row tile per block ----
__global__ __launch_bounds__(256, 2) void sse_main_kernel(
    const float* __restrict__ X, const unsigned short* __restrict__ qk,
    unsigned short* __restrict__ partials)
{
  __shared__ unsigned short Xt[128][72];   // X tile transposed [d][row]; reused as stage
  __shared__ unsigned short WTs[64][72];   // W transposed [slot][row]

  const int tid  = threadIdx.x;
  const int wave = tid >> 6;
  const int lane = tid & 63;
  const int l15  = lane & 15;
  const int g    = lane >> 4;

  const int blk  = blockIdx.x;
  const int b    = blk >> 9;               // /512
  const int tile = blk & 511;

  const float* Xb = X + (size_t)b * N_ROWS * DDIM;
  const unsigned short* qkb = qk + b * KSLOT * EH;
  const int row0 = tile * 64 + wave * 16;

  // ---- load X strip (16 rows/wave), pack bf16 A-frags, store transposed to LDS ----
  short8 a4[4];
  #pragma unroll
  for(int step = 0; step < 4; ++step){
    const float* px = Xb + (size_t)(row0 + l15) * DDIM + step * 32 + g * 8;
    f32x4 x0 = *reinterpret_cast<const f32x4*>(px);
    f32x4 x1 = *reinterpret_cast<const f32x4*>(px + 4);
    short8 a;
    a[0]=(short)f2bf(x0[0]); a[1]=(short)f2bf(x0[1]); a[2]=(short)f2bf(x0[2]); a[3]=(short)f2bf(x0[3]);
    a[4]=(short)f2bf(x1[0]); a[5]=(short)f2bf(x1[1]); a[6]=(short)f2bf(x1[2]); a[7]=(short)f2bf(x1[3]);
    a4[step] = a;
    #pragma unroll
    for(int j = 0; j < 8; ++j)
      Xt[step * 32 + g * 8 + j][wave * 16 + l15] = (unsigned short)a[j];
  }

  // ---- phase A: M-tile = X @ qk^T (B-frags from global, L2-hot) ----
  f32x4 macc[4];
  #pragma unroll
  for(int i = 0; i < 4; ++i) macc[i] = {0.f,0.f,0.f,0.f};
  #pragma unroll
  for(int step = 0; step < 4; ++step){
    #pragma unroll
    for(int st = 0; st < 4; ++st){
      short8 bq = *reinterpret_cast<const short8*>(qkb + (st * 16 + l15) * EH + step * 32 + g * 8);
      macc[st] = __builtin_amdgcn_mfma_f32_16x16x32_bf16(a4[step], bq, macc[st], 0, 0, 0);
    }
  }

  // ---- sigmoid + eps, normalize over 64 slots, W^T -> LDS ----
  float att[4][4];
  float rowsum[4];
  #pragma unroll
  for(int st = 0; st < 4; ++st){
    #pragma unroll
    for(int r = 0; r < 4; ++r)
      att[st][r] = 1.f / (1.f + __expf(-macc[st][r])) + 1e-8f;   // scale folded into qk
  }
  #pragma unroll
  for(int r = 0; r < 4; ++r){
    float s = att[0][r] + att[1][r] + att[2][r] + att[3][r];
    s += __shfl_xor(s, 1); s += __shfl_xor(s, 2);
    s += __shfl_xor(s, 4); s += __shfl_xor(s, 8);
    rowsum[r] = s;
  }
  #pragma unroll
  for(int st = 0; st < 4; ++st){
    ushort4 wp;
    wp.x = f2bf(att[st][0] / rowsum[0]);
    wp.y = f2bf(att[st][1] / rowsum[1]);
    wp.z = f2bf(att[st][2] / rowsum[2]);
    wp.w = f2bf(att[st][3] / rowsum[3]);
    *reinterpret_cast<ushort4*>(&WTs[st * 16 + l15][wave * 16 + g * 4]) = wp;
  }
  __syncthreads();   // Xt + WTs complete across all waves

  // ---- phase B: T = W^T @ X   (A=WTs[slot][row], B=Xt[d][row], k=row) ----
  f32x4 sacc[8];
  #pragma unroll
  for(int i = 0; i < 8; ++i) sacc[i] = {0.f, 0.f, 0.f, 0.f};
  #pragma unroll
  for(int ns = 0; ns < 2; ++ns){
    short8 af = *reinterpret_cast<const short8*>(&WTs[wave * 16 + l15][ns * 32 + g * 8]);
    #pragma unroll
    for(int et = 0; et < 8; ++et){
      short8 bf = *reinterpret_cast<const short8*>(&Xt[et * 16 + l15][ns * 32 + g * 8]);
      sacc[et] = __builtin_amdgcn_mfma_f32_16x16x32_bf16(af, bf, sacc[et], 0, 0, 0);
    }
  }
  __syncthreads();   // phase B reads of Xt done; safe to reuse Xt as staging

  // ---- stage T (bf16) into Xt region, then coalesced 16KB copy-out ----
  unsigned short* stage = &Xt[0][0];       // 8192 ushorts used
  #pragma unroll
  for(int et = 0; et < 8; ++et){
    #pragma unroll
    for(int r = 0; r < 4; ++r)
      stage[(wave * 16 + g * 4 + r) * 128 + et * 16 + l15] = f2bf(sacc[et][r]);
  }
  __syncthreads();
  unsigned short* po = partials + (size_t)blk * 8192;
  #pragma unroll
  for(int c = 0; c < 4; ++c){
    int idx = tid + 256 * c;               // ushort8 chunk 0..1023
    *reinterpret_cast<short8*>(po + idx * 8) =
        *reinterpret_cast<const short8*>(stage + idx * 8);
  }
}

// ---- reduce: T[b][s][:] = sum over 512 tiles, then out = T @ Wv ----
__global__ void reduce_kernel(const unsigned short* __restrict__ partials,
                              const float* __restrict__ Wv, float* __restrict__ out){
  int bs = blockIdx.x;             // 0..511 = b*64 + slot
  int b  = bs >> 6;
  int s  = bs & 63;
  __shared__ float Tl[128];
  int t = threadIdx.x;             // 128 threads = d, then e
  const unsigned short* pb = partials + (size_t)b * TILES_PER_B * 8192 + s * 128 + t;
  float acc = 0.f;
  #pragma unroll 8
  for(int i = 0; i < TILES_PER_B; ++i)
    acc += bf2f(pb[(size_t)i * 8192]);
  Tl[t] = acc;
  __syncthreads();
  float o = 0.f;
  #pragma unroll 8
  for(int d = 0; d < 128; ++d) o += Tl[d] * Wv[d * 128 + t];
  out[bs * 128 + t] = o;
}

extern "C" void kernel_launch(void* const* d_in, const int* in_sizes, int n_in,
                              void* d_out, int out_size, void* d_ws, size_t ws_size,
                              hipStream_t stream){
  const float* X  = (const float*)d_in[0];
  const float* S  = (const float*)d_in[1];
  const float* Wk = (const float*)d_in[2];
  const float* Wq = (const float*)d_in[3];
  const float* Wv = (const float*)d_in[4];
  float* out = (float*)d_out;

  char* ws = (char*)d_ws;
  unsigned short* qk       = (unsigned short*)(ws);           // 128 KB
  unsigned short* partials = (unsigned short*)(ws + 131072);  // 4096 * 16 KB = 67 MB

  hipLaunchKernelGGL(prep_qk_kernel, dim3(512), dim3(128), 0, stream, S, Wq, Wk, qk);
  hipLaunchKernelGGL(sse_main_kernel, dim3(N_BATCH * TILES_PER_B), dim3(256), 0, stream,
                     X, qk, partials);
  hipLaunchKernelGGL(reduce_kernel, dim3(512), dim3(128), 0, stream, partials, Wv, out);
}

// Round 8
// 76.962 us; speedup vs baseline: 5.1540x; 1.2184x over previous
//
#include <hip/hip_runtime.h>
#include <hip/hip_bf16.h>

typedef __attribute__((ext_vector_type(8))) short short8;
typedef __attribute__((ext_vector_type(4))) float f32x4;

#define N_BATCH 8
#define N_ROWS 32768
#define DDIM 128
#define KSLOT 64
#define EH 128
#define TPB 8                  // tiles per block
#define BLK_PER_B 64           // 512 tiles / TPB
#define SCALE 0.08838834764831845f

__device__ inline unsigned short f2bf(float f){
  unsigned int u = __builtin_bit_cast(unsigned int, f);
  u = (u + 0x7FFFu + ((u >> 16) & 1u)) >> 16;
  return (unsigned short)u;
}

__device__ inline unsigned int pk2bf(float lo, float hi){
  __hip_bfloat162 h = __float22bfloat162_rn(float2{lo, hi});
  unsigned int u;
  __builtin_memcpy(&u, &h, 4);
  return u;
}

// ---- prep: qk[b][s][d] = scale * (S[b,s,:]@Wq) @ Wk^T, bf16 ----
__global__ void prep_qk_kernel(const float* __restrict__ S, const float* __restrict__ Wq,
                               const float* __restrict__ Wk, unsigned short* __restrict__ qk){
  int bs = blockIdx.x;             // 0..511 = b*64 + slot
  __shared__ float srow[128];
  __shared__ float qrow[128];
  int t = threadIdx.x;             // 128 threads
  srow[t] = S[bs * 128 + t];
  __syncthreads();
  float acc = 0.f;
  #pragma unroll 8
  for(int h = 0; h < 128; ++h) acc += srow[h] * Wq[h * 128 + t];   // q[s,e=t]
  qrow[t] = acc;
  __syncthreads();
  float acc2 = 0.f;
  #pragma unroll 8
  for(int e = 0; e < 128; ++e) acc2 += qrow[e] * Wk[t * 128 + e];  // qk[s,d=t]
  qk[bs * 128 + t] = f2bf(acc2 * SCALE);
}

// ---- main fused kernel: 8 tiles per block, register-prefetched ----
__global__ __launch_bounds__(256, 2) void sse_main_kernel(
    const float* __restrict__ X, const unsigned short* __restrict__ qk,
    float* __restrict__ partials)
{
  __shared__ unsigned short Xt[128][70];   // X tile transposed [d][row]
  __shared__ unsigned short WTs[64][70];   // W transposed [slot][row]

  const int tid  = threadIdx.x;
  const int wave = tid >> 6;
  const int lane = tid & 63;
  const int l15  = lane & 15;
  const int g    = lane >> 4;

  const int b  = blockIdx.x >> 6;          // / BLK_PER_B
  const int tb = blockIdx.x & 63;

  const float* Xb = X + (size_t)b * N_ROWS * DDIM;
  const unsigned short* qkb = qk + b * KSLOT * EH;

  f32x4 sacc[8];   // T[slot=wave*16+g*4+r][d=et*16+l15]
  #pragma unroll
  for(int i = 0; i < 8; ++i) sacc[i] = {0.f, 0.f, 0.f, 0.f};

  // X strip base for this wave: row = tile*64 + wave*16 + l15
  const float* xw = Xb + (size_t)(tb * TPB * 64 + wave * 16 + l15) * DDIM + g * 8;

  f32x4 xa[8];     // current tile's raw X (2 f32x4 per step)
  #pragma unroll
  for(int s2 = 0; s2 < 4; ++s2){
    xa[2*s2]   = *reinterpret_cast<const f32x4*>(xw + s2 * 32);
    xa[2*s2+1] = *reinterpret_cast<const f32x4*>(xw + s2 * 32 + 4);
  }

  #pragma unroll
  for(int tt = 0; tt < TPB; ++tt){
    f32x4 xn[8];
    if(tt + 1 < TPB){
      const float* xp = xw + (size_t)(tt + 1) * 64 * DDIM;
      #pragma unroll
      for(int s2 = 0; s2 < 4; ++s2){
        xn[2*s2]   = *reinterpret_cast<const f32x4*>(xp + s2 * 32);
        xn[2*s2+1] = *reinterpret_cast<const f32x4*>(xp + s2 * 32 + 4);
      }
    }

    // ---- pack bf16 A-frags (v_cvt_pk path) + transposed store to Xt ----
    short8 a4[4];
    #pragma unroll
    for(int step = 0; step < 4; ++step){
      f32x4 x0 = xa[2*step], x1 = xa[2*step+1];
      union { short8 s; unsigned int u[4]; } pk;
      pk.u[0] = pk2bf(x0[0], x0[1]);
      pk.u[1] = pk2bf(x0[2], x0[3]);
      pk.u[2] = pk2bf(x1[0], x1[1]);
      pk.u[3] = pk2bf(x1[2], x1[3]);
      a4[step] = pk.s;
      #pragma unroll
      for(int j = 0; j < 8; ++j)
        Xt[step * 32 + g * 8 + j][wave * 16 + l15] = (unsigned short)a4[step][j];
    }

    // ---- phase A: M-tile = X @ qk^T ----
    f32x4 macc[4];
    #pragma unroll
    for(int i = 0; i < 4; ++i) macc[i] = {0.f,0.f,0.f,0.f};
    #pragma unroll
    for(int step = 0; step < 4; ++step){
      #pragma unroll
      for(int st = 0; st < 4; ++st){
        short8 bq = *reinterpret_cast<const short8*>(qkb + (st * 16 + l15) * EH + step * 32 + g * 8);
        macc[st] = __builtin_amdgcn_mfma_f32_16x16x32_bf16(a4[step], bq, macc[st], 0, 0, 0);
      }
    }

    // ---- sigmoid + eps, normalize over 64 slots, W^T -> LDS ----
    float att[4][4];
    float rinv[4];
    #pragma unroll
    for(int st = 0; st < 4; ++st){
      #pragma unroll
      for(int r = 0; r < 4; ++r)
        att[st][r] = __builtin_amdgcn_rcpf(1.f + __expf(-macc[st][r])) + 1e-8f;
    }
    #pragma unroll
    for(int r = 0; r < 4; ++r){
      float s = att[0][r] + att[1][r] + att[2][r] + att[3][r];
      s += __shfl_xor(s, 1); s += __shfl_xor(s, 2);
      s += __shfl_xor(s, 4); s += __shfl_xor(s, 8);
      rinv[r] = __builtin_amdgcn_rcpf(s);
    }
    #pragma unroll
    for(int st = 0; st < 4; ++st){
      union { unsigned int u[2]; uint2 v; } wp;
      wp.u[0] = pk2bf(att[st][0] * rinv[0], att[st][1] * rinv[1]);
      wp.u[1] = pk2bf(att[st][2] * rinv[2], att[st][3] * rinv[3]);
      *reinterpret_cast<uint2*>(&WTs[st * 16 + l15][wave * 16 + g * 4]) = wp.v;
    }
    __syncthreads();   // Xt + WTs complete across all waves (drains prefetch too — hidden)

    // ---- phase B: T += W^T @ X ----
    #pragma unroll
    for(int ns = 0; ns < 2; ++ns){
      short8 af = *reinterpret_cast<const short8*>(&WTs[wave * 16 + l15][ns * 32 + g * 8]);
      #pragma unroll
      for(int et = 0; et < 8; ++et){
        short8 bf = *reinterpret_cast<const short8*>(&Xt[et * 16 + l15][ns * 32 + g * 8]);
        sacc[et] = __builtin_amdgcn_mfma_f32_16x16x32_bf16(af, bf, sacc[et], 0, 0, 0);
      }
    }
    __syncthreads();   // protect Xt/WTs before next iteration overwrites

    if(tt + 1 < TPB){
      #pragma unroll
      for(int j = 0; j < 8; ++j) xa[j] = xn[j];
    }
  }

  // ---- write per-block partial T [64 slot][128 d] f32 ----
  float* po = partials + (size_t)blockIdx.x * (KSLOT * EH);
  #pragma unroll
  for(int et = 0; et < 8; ++et){
    #pragma unroll
    for(int r = 0; r < 4; ++r)
      po[(wave * 16 + g * 4 + r) * EH + et * 16 + l15] = sacc[et][r];
  }
}

// ---- reduce: T[b][s][:] = sum over 64 block-partials, then out = T @ Wv ----
__global__ void reduce_kernel(const float* __restrict__ partials,
                              const float* __restrict__ Wv, float* __restrict__ out){
  int bs = blockIdx.x;             // 0..511 = b*64 + slot
  int b  = bs >> 6;
  int s  = bs & 63;
  __shared__ float Tl[128];
  int t = threadIdx.x;             // 128 threads = d, then e
  const float* pb = partials + (size_t)b * BLK_PER_B * (KSLOT * EH) + s * EH + t;
  float acc = 0.f;
  #pragma unroll 8
  for(int i = 0; i < BLK_PER_B; ++i)
    acc += pb[(size_t)i * (KSLOT * EH)];
  Tl[t] = acc;
  __syncthreads();
  float o = 0.f;
  #pragma unroll 8
  for(int d = 0; d < 128; ++d) o += Tl[d] * Wv[d * 128 + t];
  out[bs * 128 + t] = o;
}

extern "C" void kernel_launch(void* const* d_in, const int* in_sizes, int n_in,
                              void* d_out, int out_size, void* d_ws, size_t ws_size,
                              hipStream_t stream){
  const float* X  = (const float*)d_in[0];
  const float* S  = (const float*)d_in[1];
  const float* Wk = (const float*)d_in[2];
  const float* Wq = (const float*)d_in[3];
  const float* Wv = (const float*)d_in[4];
  float* out = (float*)d_out;

  char* ws = (char*)d_ws;
  unsigned short* qk = (unsigned short*)(ws);           // 128 KB
  float* partials    = (float*)(ws + 131072);           // 512 * 32 KB = 16.8 MB

  hipLaunchKernelGGL(prep_qk_kernel, dim3(512), dim3(128), 0, stream, S, Wq, Wk, qk);
  hipLaunchKernelGGL(sse_main_kernel, dim3(N_BATCH * BLK_PER_B), dim3(256), 0, stream,
                     X, qk, partials);
  hipLaunchKernelGGL(reduce_kernel, dim3(512), dim3(128), 0, stream, partials, Wv, out);
}